// Round 14
// baseline (73.357 us; speedup 1.0000x reference)
//
#include <hip/hip_runtime.h>
#include <math.h>

#define EPS_CLIP 1e-6f
#define WPB 4      // b's per wave
#define NWAVES 4   // waves per block
#define NC 32      // completion sub-counters (128 B apart -> distinct lines)

struct F3 { float x, y, z; };   // 12 B -> global_load_dwordx3

typedef float v2f __attribute__((ext_vector_type(2)));

static __device__ __forceinline__ v2f pk_fma(v2f a, v2f b, v2f c) {
#if __has_builtin(__builtin_elementwise_fma)
    return __builtin_elementwise_fma(a, b, c);
#else
    v2f r; r.x = fmaf(a.x, b.x, c.x); r.y = fmaf(a.y, b.y, c.y); return r;
#endif
}

static __device__ __forceinline__ v2f mkv2(float x, float y) {
    v2f r; r.x = x; r.y = y; return r;
}

// SS = compile-time S (0 -> runtime S_rt)
template <int SS>
__global__ __launch_bounds__(256) void sym_loss_kernel(
    const float* __restrict__ R_pred,   // (B, 64, 3, 3)
    const float* __restrict__ R_gt,     // (B, 3, 3)
    const float* __restrict__ rot,      // (S, 3, 3)
    float* __restrict__ partial,        // (gridDim.x,)
    unsigned int* __restrict__ cnts,    // NC counters, stride 32 uints; master at [NC*32]
    float* __restrict__ out,
    int S_rt, float invB)
{
    const int S    = SS ? SS : S_rt;
    const int tid  = threadIdx.x;
    const int lane = tid & 63;
    const int wid  = tid >> 6;
    const int gw   = __builtin_amdgcn_readfirstlane(blockIdx.x * NWAVES + wid);
    const int b0   = gw * WPB;

    // per-lane base: candidate `lane` of rotation b0; next b = +192 F3
    const F3* base = reinterpret_cast<const F3*>(R_pred) + ((size_t)b0 * 64 + lane) * 3;

    // ---- hoist ALL G loads above the loop (uniform -> s_load) ----
    float g[WPB][9];
    #pragma unroll
    for (int k = 0; k < WPB; ++k) {
        const float* G = R_gt + (size_t)(b0 + k) * 9;
        #pragma unroll
        for (int e = 0; e < 9; ++e) g[k][e] = G[e];
    }

    // ---- 3-slot register ring, prefetch distance 2 ----
    F3 A[3][3];
    #pragma unroll
    for (int r = 0; r < 3; ++r) A[0][r] = base[r];
    #pragma unroll
    for (int r = 0; r < 3; ++r) A[1][r] = base[192 + r];

    float mk[WPB];   // per-LANE max over s (no cross-lane work inside the loop)

    #pragma unroll
    for (int k = 0; k < WPB; ++k) {
        if (k + 2 < WPB) {
            #pragma unroll
            for (int r = 0; r < 3; ++r)
                A[(k + 2) % 3][r] = base[(size_t)(k + 2) * 192 + r];
        }
        const int slot = k % 3;       // compile-time after unroll

        const float p[9] = { A[slot][0].x, A[slot][0].y, A[slot][0].z,
                             A[slot][1].x, A[slot][1].y, A[slot][1].z,
                             A[slot][2].x, A[slot][2].y, A[slot][2].z };

        // Q = P * G^T (27 FMA);  trace(P @ (rot_s @ G)^T) = <Q, rot_s>  (cyclic trace)
        float q[9];
        #pragma unroll
        for (int i = 0; i < 3; ++i)
            #pragma unroll
            for (int j = 0; j < 3; ++j)
                q[i * 3 + j] = fmaf(p[i * 3 + 0], g[k][j * 3 + 0],
                               fmaf(p[i * 3 + 1], g[k][j * 3 + 1],
                                    p[i * 3 + 2] * g[k][j * 3 + 2]));

        // packed dots: 4 v_pk_fma_f32 + 1 add + 1 fma per sym op
        const v2f q01 = mkv2(q[0], q[1]), q23 = mkv2(q[2], q[3]),
                  q45 = mkv2(q[4], q[5]), q67 = mkv2(q[6], q[7]);
        const float q8 = q[8];

        float tr[12 > SS ? 12 : SS];
        if (SS) {
            #pragma unroll
            for (int s = 0; s < SS; ++s) {
                const float* Rs = rot + s * 9;
                v2f acc = q01 * mkv2(Rs[0], Rs[1]);
                acc = pk_fma(q23, mkv2(Rs[2], Rs[3]), acc);
                acc = pk_fma(q45, mkv2(Rs[4], Rs[5]), acc);
                acc = pk_fma(q67, mkv2(Rs[6], Rs[7]), acc);
                tr[s] = fmaf(q8, Rs[8], acc.x + acc.y);
            }
            float m;
            if (SS == 12) {   // balanced tree, v_max3-fusable
                const float a = fmaxf(fmaxf(tr[0], tr[1]), tr[2]);
                const float bb = fmaxf(fmaxf(tr[3], tr[4]), tr[5]);
                const float c = fmaxf(fmaxf(tr[6], tr[7]), tr[8]);
                const float d = fmaxf(fmaxf(tr[9], tr[10]), tr[11]);
                m = fmaxf(fmaxf(a, bb), fmaxf(c, d));
            } else {
                m = tr[0];
                #pragma unroll
                for (int s = 1; s < SS; ++s) m = fmaxf(m, tr[s]);
            }
            mk[k] = m;
        } else {
            float m = -1e30f;
            for (int s = 0; s < S; ++s) {
                const float* Rs = rot + s * 9;
                float t = 0.f;
                #pragma unroll
                for (int e = 0; e < 9; ++e) t = fmaf(q[e], Rs[e], t);
                m = fmaxf(m, t);
            }
            mk[k] = m;
        }
    }

    // ---- deferred cross-lane reduce: 6 rounds x 4 independent chains ----
    #pragma unroll
    for (int off = 32; off; off >>= 1) {
        #pragma unroll
        for (int k = 0; k < WPB; ++k)
            mk[k] = fmaxf(mk[k], __shfl_xor(mk[k], off));
    }

    // ---- batched acos: lanes 0..3 take one wave max each, single acosf ----
    float mv = mk[0];
    #pragma unroll
    for (int k = 1; k < WPB; ++k) mv = (lane == k) ? mk[k] : mv;
    float cosv = (mv - 1.0f) * 0.5f;
    cosv = fminf(fmaxf(cosv, -1.0f + EPS_CLIP), 1.0f - EPS_CLIP);
    float a = (lane < WPB) ? acosf(cosv) : 0.0f;  // min over (c,s) arccos == arccos(max trace)
    a += __shfl_xor(a, 1);
    a += __shfl_xor(a, 2);

    __shared__ float sLoss[NWAVES];
    if (lane == 0) sLoss[wid] = a;
    __syncthreads();

    // ---- fused finalize: HIERARCHICAL last-block-done (no same-line pileup) ----
    // 32 sub-counters on distinct lines absorb 2048 signals (64 each, spread over
    // the blocks' natural finish stagger); 32 "line-closer" blocks signal master.
    // release->acquire chains via sub-counter RMW then master RMW give the final
    // block visibility of all partials; fixed index order -> bit-deterministic.
    if (tid == 0) {
        float bsum = 0.f;
        #pragma unroll
        for (int i = 0; i < NWAVES; ++i) bsum += sLoss[i];
        __hip_atomic_store(&partial[blockIdx.x], bsum,
                           __ATOMIC_RELAXED, __HIP_MEMORY_SCOPE_AGENT);
        const unsigned c = blockIdx.x & (NC - 1);
        const unsigned q = (gridDim.x >> 5) + ((c < (gridDim.x & (NC - 1))) ? 1u : 0u);
        unsigned flag = 0u;
        unsigned prev = __hip_atomic_fetch_add(&cnts[c * 32], 1u,
                           __ATOMIC_ACQ_REL, __HIP_MEMORY_SCOPE_AGENT);
        if (prev == q - 1u) {   // last block on this sub-counter
            const unsigned mt = (gridDim.x < NC) ? gridDim.x : NC;
            unsigned mp = __hip_atomic_fetch_add(&cnts[NC * 32], 1u,
                              __ATOMIC_ACQ_REL, __HIP_MEMORY_SCOPE_AGENT);
            flag = (mp == mt - 1u) ? 1u : 0u;
        }
        sLoss[0] = (float)flag;
    }
    __syncthreads();

    if (sLoss[0] != 0.0f) {     // final block only
        const int n = gridDim.x;
        float sum = 0.f;
        for (int i = tid; i < n; i += 256)
            sum += __hip_atomic_load(&partial[i],
                       __ATOMIC_RELAXED, __HIP_MEMORY_SCOPE_AGENT);
        #pragma unroll
        for (int off = 32; off; off >>= 1) sum += __shfl_xor(sum, off);
        __shared__ float ws2[NWAVES];
        if (lane == 0) ws2[wid] = sum;
        __syncthreads();
        if (tid == 0) {
            float t = 0.f;
            #pragma unroll
            for (int i = 0; i < NWAVES; ++i) t += ws2[i];
            out[0] = t * invB;
        }
    }
}

extern "C" void kernel_launch(void* const* d_in, const int* in_sizes, int n_in,
                              void* d_out, int out_size, void* d_ws, size_t ws_size,
                              hipStream_t stream) {
    const float* R_pred = (const float*)d_in[0];
    const float* R_gt   = (const float*)d_in[1];
    const float* rot    = (const float*)d_in[2];
    float* out = (float*)d_out;

    const int B = in_sizes[1] / 9;                 // 32768
    const int S = in_sizes[2] / 9;                 // 12
    const int nBlocks = B / (WPB * NWAVES);        // 2048

    float* partial = (float*)d_ws;                              // nBlocks floats (8 KB)
    unsigned* cnts = (unsigned*)((char*)d_ws + (size_t)nBlocks * sizeof(float));

    // zero NC sub-counters (stride 32 uints) + master: (NC*32+1)*4 = 4228 B
    hipMemsetAsync(cnts, 0, (NC * 32 + 1) * sizeof(unsigned), stream);

    if (S == 12)
        sym_loss_kernel<12><<<nBlocks, 256, 0, stream>>>(
            R_pred, R_gt, rot, partial, cnts, out, S, 1.0f / (float)B);
    else
        sym_loss_kernel<0><<<nBlocks, 256, 0, stream>>>(
            R_pred, R_gt, rot, partial, cnts, out, S, 1.0f / (float)B);
}

// Round 15
// 21.369 us; speedup vs baseline: 3.4329x; 3.4329x over previous
//
#include <hip/hip_runtime.h>
#include <math.h>

#define EPS_CLIP 1e-6f
#define WPB 4      // b's per wave
#define NWAVES 4   // waves per block

struct F3 { float x, y, z; };   // 12 B -> global_load_dwordx3

typedef float v2f __attribute__((ext_vector_type(2)));

static __device__ __forceinline__ v2f pk_fma(v2f a, v2f b, v2f c) {
#if __has_builtin(__builtin_elementwise_fma)
    return __builtin_elementwise_fma(a, b, c);
#else
    v2f r; r.x = fmaf(a.x, b.x, c.x); r.y = fmaf(a.y, b.y, c.y); return r;
#endif
}

static __device__ __forceinline__ v2f mkv2(float x, float y) {
    v2f r; r.x = x; r.y = y; return r;
}

// SS = compile-time S (0 -> runtime S_rt)
template <int SS>
__global__ __launch_bounds__(256) void sym_loss_kernel(
    const float* __restrict__ R_pred,   // (B, 64, 3, 3)
    const float* __restrict__ R_gt,     // (B, 3, 3)
    const float* __restrict__ rot,      // (S, 3, 3)
    float* __restrict__ partial,        // (gridDim.x,)
    int S_rt)
{
    const int S    = SS ? SS : S_rt;
    const int tid  = threadIdx.x;
    const int lane = tid & 63;
    const int wid  = tid >> 6;
    const int gw   = __builtin_amdgcn_readfirstlane(blockIdx.x * NWAVES + wid);
    const int b0   = gw * WPB;

    // per-lane base: candidate `lane` of rotation b0; next b = +192 F3
    const F3* base = reinterpret_cast<const F3*>(R_pred) + ((size_t)b0 * 64 + lane) * 3;

    // ---- hoist ALL G loads above the loop (uniform -> s_load, 36 SGPRs) ----
    float g[WPB][9];
    #pragma unroll
    for (int k = 0; k < WPB; ++k) {
        const float* G = R_gt + (size_t)(b0 + k) * 9;
        #pragma unroll
        for (int e = 0; e < 9; ++e) g[k][e] = G[e];
    }

    // ---- 3-slot register ring, prefetch distance 2 ----
    F3 A[3][3];
    #pragma unroll
    for (int r = 0; r < 3; ++r) A[0][r] = base[r];
    #pragma unroll
    for (int r = 0; r < 3; ++r) A[1][r] = base[192 + r];

    float mk[WPB];   // per-LANE max over s (no cross-lane work inside the loop)

    #pragma unroll
    for (int k = 0; k < WPB; ++k) {
        if (k + 2 < WPB) {
            #pragma unroll
            for (int r = 0; r < 3; ++r)
                A[(k + 2) % 3][r] = base[(size_t)(k + 2) * 192 + r];
        }
        const int slot = k % 3;       // compile-time after unroll

        const float p[9] = { A[slot][0].x, A[slot][0].y, A[slot][0].z,
                             A[slot][1].x, A[slot][1].y, A[slot][1].z,
                             A[slot][2].x, A[slot][2].y, A[slot][2].z };

        // Q = P * G^T (27 FMA);  trace(P @ (rot_s @ G)^T) = <Q, rot_s>  (cyclic trace)
        float q[9];
        #pragma unroll
        for (int i = 0; i < 3; ++i)
            #pragma unroll
            for (int j = 0; j < 3; ++j)
                q[i * 3 + j] = fmaf(p[i * 3 + 0], g[k][j * 3 + 0],
                               fmaf(p[i * 3 + 1], g[k][j * 3 + 1],
                                    p[i * 3 + 2] * g[k][j * 3 + 2]));

        // packed dots: 4 v_pk_fma_f32 + 1 add + 1 fma per sym op (vs 9 scalar FMA)
        const v2f q01 = mkv2(q[0], q[1]), q23 = mkv2(q[2], q[3]),
                  q45 = mkv2(q[4], q[5]), q67 = mkv2(q[6], q[7]);
        const float q8 = q[8];

        float tr[12 > SS ? 12 : SS];
        if (SS) {
            #pragma unroll
            for (int s = 0; s < SS; ++s) {
                const float* Rs = rot + s * 9;
                v2f acc = q01 * mkv2(Rs[0], Rs[1]);
                acc = pk_fma(q23, mkv2(Rs[2], Rs[3]), acc);
                acc = pk_fma(q45, mkv2(Rs[4], Rs[5]), acc);
                acc = pk_fma(q67, mkv2(Rs[6], Rs[7]), acc);
                tr[s] = fmaf(q8, Rs[8], acc.x + acc.y);
            }
            float m;
            if (SS == 12) {   // balanced tree, v_max3-fusable
                const float a = fmaxf(fmaxf(tr[0], tr[1]), tr[2]);
                const float bb = fmaxf(fmaxf(tr[3], tr[4]), tr[5]);
                const float c = fmaxf(fmaxf(tr[6], tr[7]), tr[8]);
                const float d = fmaxf(fmaxf(tr[9], tr[10]), tr[11]);
                m = fmaxf(fmaxf(a, bb), fmaxf(c, d));
            } else {
                m = tr[0];
                #pragma unroll
                for (int s = 1; s < SS; ++s) m = fmaxf(m, tr[s]);
            }
            mk[k] = m;
        } else {
            float m = -1e30f;
            for (int s = 0; s < S; ++s) {
                const float* Rs = rot + s * 9;
                float t = 0.f;
                #pragma unroll
                for (int e = 0; e < 9; ++e) t = fmaf(q[e], Rs[e], t);
                m = fmaxf(m, t);
            }
            mk[k] = m;
        }
    }

    // ---- deferred cross-lane reduce: 6 rounds x 4 independent chains ----
    #pragma unroll
    for (int off = 32; off; off >>= 1) {
        #pragma unroll
        for (int k = 0; k < WPB; ++k)
            mk[k] = fmaxf(mk[k], __shfl_xor(mk[k], off));
    }

    // ---- batched acos: lanes 0..3 take one wave max each, single acosf ----
    float mv = mk[0];
    #pragma unroll
    for (int k = 1; k < WPB; ++k) mv = (lane == k) ? mk[k] : mv;
    float cosv = (mv - 1.0f) * 0.5f;
    cosv = fminf(fmaxf(cosv, -1.0f + EPS_CLIP), 1.0f - EPS_CLIP);
    float a = (lane < WPB) ? acosf(cosv) : 0.0f;  // min over (c,s) arccos == arccos(max trace)
    a += __shfl_xor(a, 1);
    a += __shfl_xor(a, 2);

    __shared__ float sLoss[NWAVES];
    if (lane == 0) sLoss[wid] = a;
    __syncthreads();
    if (tid == 0) {
        float sum = 0.f;
        #pragma unroll
        for (int i = 0; i < NWAVES; ++i) sum += sLoss[i];
        partial[blockIdx.x] = sum;
    }
}

__global__ __launch_bounds__(1024) void reduce_kernel(
    const float* __restrict__ partial, int n, float* __restrict__ out, float invB)
{
    float sum = 0.f;
    for (int i = threadIdx.x; i < n; i += 1024) sum += partial[i];
    #pragma unroll
    for (int off = 32; off; off >>= 1) sum += __shfl_xor(sum, off);
    __shared__ float ws[16];
    const int w = threadIdx.x >> 6;
    if ((threadIdx.x & 63) == 0) ws[w] = sum;
    __syncthreads();
    if (threadIdx.x == 0) {
        float t = 0.f;
        #pragma unroll
        for (int i = 0; i < 16; ++i) t += ws[i];
        out[0] = t * invB;
    }
}

extern "C" void kernel_launch(void* const* d_in, const int* in_sizes, int n_in,
                              void* d_out, int out_size, void* d_ws, size_t ws_size,
                              hipStream_t stream) {
    const float* R_pred = (const float*)d_in[0];
    const float* R_gt   = (const float*)d_in[1];
    const float* rot    = (const float*)d_in[2];
    float* out = (float*)d_out;

    const int B = in_sizes[1] / 9;                 // 32768
    const int S = in_sizes[2] / 9;                 // 12
    const int nBlocks = B / (WPB * NWAVES);        // 2048

    float* partial = (float*)d_ws;                 // nBlocks * 4 B

    if (S == 12)
        sym_loss_kernel<12><<<nBlocks, 256, 0, stream>>>(R_pred, R_gt, rot, partial, S);
    else
        sym_loss_kernel<0><<<nBlocks, 256, 0, stream>>>(R_pred, R_gt, rot, partial, S);

    reduce_kernel<<<1, 1024, 0, stream>>>(partial, nBlocks, out, 1.0f / (float)B);
}